// Round 7
// baseline (160.200 us; speedup 1.0000x reference)
//
#include <hip/hip_runtime.h>
#include <math.h>

#define HID 4096
#define NEXP 64
#define NTOK 16384

typedef __attribute__((ext_vector_type(8))) short short8;
typedef __attribute__((ext_vector_type(8))) __bf16 bf16x8;
typedef __attribute__((ext_vector_type(4))) float f32x4;

// ---- Kernel 0: convert W[k][e] fp32 -> hi/lo bf16 in B-fragment-linear order
// Wfrag[((ks*4 + nt)*64 + lane)*8 + j] = W[ks*32 + (lane>>4)*8 + j][nt*16 + (lane&15)]
__global__ __launch_bounds__(256) void wfrag_kernel(
    const float* __restrict__ W, short* __restrict__ wfh,
    short* __restrict__ wfl) {
  int gid = blockIdx.x * 256 + threadIdx.x;  // 0 .. 32767
  int l  = gid & 63;
  int nt = (gid >> 6) & 3;
  int ks = gid >> 8;                         // 0 .. 127
  int e  = nt * 16 + (l & 15);
  int k0 = ks * 32 + (l >> 4) * 8;
  bf16x8 h8, l8;
#pragma unroll
  for (int j = 0; j < 8; ++j) {
    float w = W[(size_t)(k0 + j) * NEXP + e];
    __bf16 h = (__bf16)w;         // RNE
    h8[j] = h;
    l8[j] = (__bf16)(w - (float)h);
  }
  ((short8*)wfh)[gid] = __builtin_bit_cast(short8, h8);
  ((short8*)wfl)[gid] = __builtin_bit_cast(short8, l8);
}

// ---- Kernel 1: MFMA GEMM, K split across 4 waves, software-pipelined -------
// Block = 16 tokens, 4 waves = 4 K-quarters. Explicit double-buffering:
// B-frags for iter i+1 and x for iter i+2 are issued before iter i's MFMAs,
// so each wave keeps ~10 loads in flight instead of serializing load->use.
__global__ __launch_bounds__(256, 3) void router_main(
    const float* __restrict__ x, const short* __restrict__ wfh,
    const short* __restrict__ wfl, const float* __restrict__ b,
    float* __restrict__ out_exp, float* __restrict__ out_prob,
    float* __restrict__ out_k, unsigned int* __restrict__ flag_count,
    int* __restrict__ flag_list) {
  __shared__ float partial[4][16][NEXP];  // 16 KB

  const int t = threadIdx.x;
  const int q = t >> 6;    // wave = K-quarter
  const int l = t & 63;    // lane
  const int m0 = blockIdx.x * 16;

  // A-frag source: row = m0 + (l&15), k = q*1024 + i*32 + (l>>4)*8 + j
  const float* xptr =
      x + (size_t)(m0 + (l & 15)) * HID + q * (HID / 4) + (l >> 4) * 8;
  const short8* wfh8 = (const short8*)wfh;
  const short8* wfl8 = (const short8*)wfl;

  f32x4 acc[4];
#pragma unroll
  for (int nt = 0; nt < 4; ++nt) acc[nt] = (f32x4){0.f, 0.f, 0.f, 0.f};

  // pipeline buffers
  float4 xb[2][2];
  short8 bh[2][4], bl[2][4];

  // prologue: x(0), x(1), B(0)
  xb[0][0] = *(const float4*)(xptr + 0);
  xb[0][1] = *(const float4*)(xptr + 4);
  xb[1][0] = *(const float4*)(xptr + 32);
  xb[1][1] = *(const float4*)(xptr + 36);
  {
    const int wb = (q * 32) * 256 + l;
#pragma unroll
    for (int nt = 0; nt < 4; ++nt) {
      bh[0][nt] = wfh8[wb + nt * 64];
      bl[0][nt] = wfl8[wb + nt * 64];
    }
  }

#pragma unroll 4
  for (int i = 0; i < 32; ++i) {
    const int cur = i & 1;

    // 1. convert current x tile to hi/lo bf16
    float xv[8];
    *(float4*)&xv[0] = xb[cur][0];
    *(float4*)&xv[4] = xb[cur][1];
    bf16x8 ah, al;
#pragma unroll
    for (int j = 0; j < 8; ++j) {
      __bf16 h = (__bf16)xv[j];
      ah[j] = h;
      al[j] = (__bf16)(xv[j] - (float)h);
    }

    // 2. issue B loads for iter i+1 (masked tail: reloads 31, never used)
    {
      const int nb = (i + 1) & 31;
      const int bs = (i + 1) & 1;
      const int wb = (q * 32 + nb) * 256 + l;
#pragma unroll
      for (int nt = 0; nt < 4; ++nt) {
        bh[bs][nt] = wfh8[wb + nt * 64];
        bl[bs][nt] = wfl8[wb + nt * 64];
      }
    }

    // 3. issue x loads for iter i+2 into the slot just consumed
    {
      const int nx = (i + 2) & 31;
      xb[cur][0] = *(const float4*)(xptr + nx * 32);
      xb[cur][1] = *(const float4*)(xptr + nx * 32 + 4);
    }

    // 4. MFMAs for iter i (B was issued at iter i-1: latency already hidden)
#pragma unroll
    for (int nt = 0; nt < 4; ++nt) {
      acc[nt] = __builtin_amdgcn_mfma_f32_16x16x32_bf16(ah, bh[cur][nt], acc[nt], 0, 0, 0);
      acc[nt] = __builtin_amdgcn_mfma_f32_16x16x32_bf16(al, bh[cur][nt], acc[nt], 0, 0, 0);
      acc[nt] = __builtin_amdgcn_mfma_f32_16x16x32_bf16(ah, bl[cur][nt], acc[nt], 0, 0, 0);
      acc[nt] = __builtin_amdgcn_mfma_f32_16x16x32_bf16(al, bl[cur][nt], acc[nt], 0, 0, 0);
    }
  }

  // D layout: row (token) = (l>>4)*4 + r, col (expert) = nt*16 + (l&15)
#pragma unroll
  for (int nt = 0; nt < 4; ++nt)
#pragma unroll
    for (int r = 0; r < 4; ++r)
      partial[q][(l >> 4) * 4 + r][nt * 16 + (l & 15)] = acc[nt][r];
  __syncthreads();

  // ---------------- routing (fp32; fp64 repair net catches close calls) ----
  const float bias = b[l];
  for (int it = 0; it < 4; ++it) {
    const int tl = q * 4 + it;   // wave q routes tokens q*4 .. q*4+3
    float lgv = (partial[0][tl][l] + partial[1][tl][l]) +
                (partial[2][tl][l] + partial[3][tl][l]) + bias;

    float mx = lgv;
#pragma unroll
    for (int off = 32; off; off >>= 1) mx = fmaxf(mx, __shfl_xor(mx, off));
    float ev = expf(lgv - mx);
    float sm = ev;
#pragma unroll
    for (int off = 32; off; off >>= 1) sm += __shfl_xor(sm, off);
    float p = ev / sm;

    // bitonic sort: descending by p, ties by ascending index
    float sp = p;
    int   si = l;
#pragma unroll
    for (int k = 2; k <= 64; k <<= 1) {
#pragma unroll
      for (int j = k >> 1; j > 0; j >>= 1) {
        float op = __shfl_xor(sp, j);
        int   oi = __shfl_xor(si, j);
        bool cmp  = (sp > op) || (sp == op && si < oi);
        bool keep = (cmp == (((l & k) == 0) == ((l & j) == 0)));
        if (!keep) { sp = op; si = oi; }
      }
    }

    // inclusive prefix sum
    float c = sp;
#pragma unroll
    for (int off = 1; off < 64; off <<= 1) {
      float tp = __shfl_up(c, off);
      if (l >= off) c += tp;
    }

    unsigned long long m = __ballot(c >= 0.8f);
    int kv = (m == 0ULL) ? NEXP : __ffsll(m);

    // ambiguity flags (margins >> split-bf16 logit error ~2e-5)
    float spn = __shfl_down(sp, 1);
    bool pairRisk = (l < kv) && (l < 63) && ((sp - spn) < 1e-3f * (sp + spn));
    bool cumRisk  = fabsf(c - 0.8f) < 3e-4f;
    bool flagged  = (__ballot(pairRisk || cumRisk) != 0ULL);

    bool sel = l < kv;
    const int tok = m0 + tl;
    size_t base = (size_t)tok * NEXP;
    out_exp[base + l]  = sel ? (float)si : -1.0f;
    out_prob[base + l] = sel ? sp : 0.0f;
    if (l == 0) {
      out_k[tok] = (float)kv;
      if (flagged) {
        unsigned int idx = atomicAdd(flag_count, 1u);
        flag_list[idx] = tok;
      }
    }
  }
}

// ---- Kernel 2: fp64 exact repair of flagged tokens -------------------------
__global__ __launch_bounds__(256) void router_repair(
    const float* __restrict__ x, const float* __restrict__ W,
    const float* __restrict__ b, const unsigned int* __restrict__ flag_count,
    const int* __restrict__ flag_list, float* __restrict__ out_exp,
    float* __restrict__ out_prob, float* __restrict__ out_k) {
  __shared__ double part[4][NEXP];
  const int t = threadIdx.x;
  const int e = t & 63;
  const int c = t >> 6;
  const int n = (int)*flag_count;

  for (int i = blockIdx.x; i < n; i += gridDim.x) {
    const int tok = flag_list[i];
    const float* xrow = x + (size_t)tok * HID;
    double s = 0.0;
    const int k0 = c * (HID / 4);
#pragma unroll 8
    for (int k = k0; k < k0 + HID / 4; ++k)
      s = fma((double)xrow[k], (double)W[(size_t)k * NEXP + e], s);
    part[c][e] = s;
    __syncthreads();

    if (t < 64) {
      double lgv = ((part[0][e] + part[1][e]) + part[2][e]) + part[3][e] +
                   (double)b[e];
      double mx = lgv;
#pragma unroll
      for (int off = 32; off; off >>= 1) mx = fmax(mx, __shfl_xor(mx, off));
      double ev = exp(lgv - mx);
      double sm = ev;
#pragma unroll
      for (int off = 32; off; off >>= 1) sm += __shfl_xor(sm, off);
      double p = ev / sm;

      double sp = p;
      int    si = e;
#pragma unroll
      for (int k = 2; k <= 64; k <<= 1) {
#pragma unroll
        for (int j = k >> 1; j > 0; j >>= 1) {
          double op = __shfl_xor(sp, j);
          int    oi = __shfl_xor(si, j);
          bool cmp  = (sp > op) || (sp == op && si < oi);
          bool keep = (cmp == (((e & k) == 0) == ((e & j) == 0)));
          if (!keep) { sp = op; si = oi; }
        }
      }

      double cc = sp;
#pragma unroll
      for (int off = 1; off < 64; off <<= 1) {
        double tp = __shfl_up(cc, off);
        if (e >= off) cc += tp;
      }

      unsigned long long m = __ballot(cc >= 0.8);
      int kv = (m == 0ULL) ? NEXP : __ffsll(m);

      bool sel = e < kv;
      size_t base = (size_t)tok * NEXP;
      out_exp[base + e]  = sel ? (float)si : -1.0f;
      out_prob[base + e] = sel ? (float)sp : 0.0f;
      if (e == 0) out_k[tok] = (float)kv;
    }
    __syncthreads();
  }
}

extern "C" void kernel_launch(void* const* d_in, const int* in_sizes, int n_in,
                              void* d_out, int out_size, void* d_ws,
                              size_t ws_size, hipStream_t stream) {
  const float* x = (const float*)d_in[0];
  const float* W = (const float*)d_in[1];
  const float* b = (const float*)d_in[2];

  float* out_exp  = (float*)d_out;
  float* out_prob = out_exp + (size_t)NTOK * NEXP;
  float* out_k    = out_prob + (size_t)NTOK * NEXP;

  short* wfh = (short*)d_ws;                                   // 512 KB
  short* wfl = (short*)((char*)d_ws + (size_t)512 * 1024);     // 512 KB
  unsigned int* flag_count = (unsigned int*)((char*)d_ws + (size_t)1024 * 1024);
  int* flag_list = (int*)((char*)d_ws + (size_t)1024 * 1024 + 256);

  hipMemsetAsync(flag_count, 0, 4, stream);

  wfrag_kernel<<<128, 256, 0, stream>>>(W, wfh, wfl);
  router_main<<<NTOK / 16, 256, 0, stream>>>(x, wfh, wfl, b, out_exp,
                                             out_prob, out_k, flag_count,
                                             flag_list);
  router_repair<<<128, 256, 0, stream>>>(x, W, b, flag_count, flag_list,
                                         out_exp, out_prob, out_k);
}

// Round 8
// 147.592 us; speedup vs baseline: 1.0854x; 1.0854x over previous
//
#include <hip/hip_runtime.h>
#include <math.h>

#define HID 4096
#define NEXP 64
#define NTOK 16384
#define NCH 16   // K-chunks per wave-quarter, 64 floats each

typedef __attribute__((ext_vector_type(8))) short short8;
typedef __attribute__((ext_vector_type(8))) __bf16 bf16x8;
typedef __attribute__((ext_vector_type(4))) float f32x4;

// ---- Kernel 0: convert W[k][e] fp32 -> hi/lo bf16 in B-fragment-linear order
__global__ __launch_bounds__(256) void wfrag_kernel(
    const float* __restrict__ W, short* __restrict__ wfh,
    short* __restrict__ wfl) {
  int gid = blockIdx.x * 256 + threadIdx.x;  // 0 .. 32767
  int l  = gid & 63;
  int nt = (gid >> 6) & 3;
  int ks = gid >> 8;                         // 0 .. 127
  int e  = nt * 16 + (l & 15);
  int k0 = ks * 32 + (l >> 4) * 8;
  bf16x8 h8, l8;
#pragma unroll
  for (int j = 0; j < 8; ++j) {
    float w = W[(size_t)(k0 + j) * NEXP + e];
    __bf16 h = (__bf16)w;         // RNE
    h8[j] = h;
    l8[j] = (__bf16)(w - (float)h);
  }
  ((short8*)wfh)[gid] = __builtin_bit_cast(short8, h8);
  ((short8*)wfl)[gid] = __builtin_bit_cast(short8, l8);
}

// ---- Kernel 1: MFMA GEMM with async global_load_lds staging of x -----------
// Block = 16 tokens, 4 waves = 4 K-quarters. Each wave stages its 4 KB x-chunk
// into a PRIVATE LDS double-buffer (no cross-wave barrier) via 4x
// global_load_lds dwordx4, fenced with counted vmcnt(4) (vmcnt(0) only on the
// final chunk). LDS layout is fragment-ordered with granule-XOR swizzle
// (both-sides: pre-swizzled global source + swizzled ds_read) =>
// coalesced 256B-row staging AND conflict-free ds_read_b128.
__global__ __launch_bounds__(256, 3) void router_main(
    const float* __restrict__ x, const short* __restrict__ wfh,
    const short* __restrict__ wfl, const float* __restrict__ b,
    float* __restrict__ out_exp, float* __restrict__ out_prob,
    float* __restrict__ out_k, unsigned int* __restrict__ flag_count,
    int* __restrict__ flag_list) {
  __shared__ float xstage[4][2][1024];    // 32 KB: [wave][dbuf][16rowsx256B]
  __shared__ float partial[4][16][NEXP];  // 16 KB

  const int t = threadIdx.x;
  const int q = t >> 6;    // wave = K-quarter
  const int l = t & 63;    // lane
  const int m0 = blockIdx.x * 16;
  const int kq = q * (HID / 4);

  // staging source pointers: instr n covers rows 4n..4n+3; lane l -> row
  // r = 4n + (l>>4), stored granule s = l&15, logical granule g = s ^ (r&7)
  const float* xp[4];
#pragma unroll
  for (int n = 0; n < 4; ++n) {
    int r = n * 4 + (l >> 4);
    int g = (l & 15) ^ (r & 7);
    xp[n] = x + (size_t)(m0 + r) * HID + kq + g * 4;
  }

  const short8* wfh8 = (const short8*)wfh;
  const short8* wfl8 = (const short8*)wfl;

  f32x4 acc[4];
#pragma unroll
  for (int nt = 0; nt < 4; ++nt) acc[nt] = (f32x4){0.f, 0.f, 0.f, 0.f};

  // prologue: stage chunk 0 into buffer 0
#pragma unroll
  for (int n = 0; n < 4; ++n)
    __builtin_amdgcn_global_load_lds(xp[n], &xstage[q][0][n * 256], 16, 0, 0);

  const char* wavebase = (const char*)&xstage[q][0][0];

  for (int ch = 0; ch < NCH; ++ch) {
    // stage next chunk into the other buffer, then fence so the CURRENT
    // chunk (all ops older than the 4 just issued) is complete.
    if (ch + 1 < NCH) {
#pragma unroll
      for (int n = 0; n < 4; ++n)
        __builtin_amdgcn_global_load_lds(xp[n] + (ch + 1) * 64,
                                         &xstage[q][(ch + 1) & 1][n * 256],
                                         16, 0, 0);
      asm volatile("s_waitcnt vmcnt(4)" ::: "memory");
    } else {
      asm volatile("s_waitcnt vmcnt(0)" ::: "memory");
    }
    __builtin_amdgcn_sched_barrier(0);

    // compute chunk ch from buffer ch&1
    const char* rowbase = wavebase + (ch & 1) * 4096 + (l & 15) * 256;
#pragma unroll
    for (int kk = 0; kk < 2; ++kk) {
      int s0 = ((kk * 8 + (l >> 4) * 2) ^ (l & 7)) * 16;
      float4 lo = *(const float4*)(rowbase + s0);
      float4 hi = *(const float4*)(rowbase + (s0 ^ 16));
      float xv[8] = {lo.x, lo.y, lo.z, lo.w, hi.x, hi.y, hi.z, hi.w};
      bf16x8 ah, al;
#pragma unroll
      for (int j = 0; j < 8; ++j) {
        __bf16 h = (__bf16)xv[j];
        ah[j] = h;
        al[j] = (__bf16)(xv[j] - (float)h);
      }
      const int wb = (q * 32 + ch * 2 + kk) * 256 + l;
#pragma unroll
      for (int nt = 0; nt < 4; ++nt) {
        bf16x8 bh = __builtin_bit_cast(bf16x8, wfh8[wb + nt * 64]);
        bf16x8 bl = __builtin_bit_cast(bf16x8, wfl8[wb + nt * 64]);
        acc[nt] = __builtin_amdgcn_mfma_f32_16x16x32_bf16(ah, bh, acc[nt], 0, 0, 0);
        acc[nt] = __builtin_amdgcn_mfma_f32_16x16x32_bf16(al, bh, acc[nt], 0, 0, 0);
        acc[nt] = __builtin_amdgcn_mfma_f32_16x16x32_bf16(ah, bl, acc[nt], 0, 0, 0);
        acc[nt] = __builtin_amdgcn_mfma_f32_16x16x32_bf16(al, bl, acc[nt], 0, 0, 0);
      }
    }
  }

  // D layout: row (token) = (l>>4)*4 + r, col (expert) = nt*16 + (l&15)
#pragma unroll
  for (int nt = 0; nt < 4; ++nt)
#pragma unroll
    for (int r = 0; r < 4; ++r)
      partial[q][(l >> 4) * 4 + r][nt * 16 + (l & 15)] = acc[nt][r];
  __syncthreads();

  // ---------------- routing (fp32; fp64 repair net catches close calls) ----
  const float bias = b[l];
  for (int it = 0; it < 4; ++it) {
    const int tl = q * 4 + it;   // wave q routes tokens q*4 .. q*4+3
    float lgv = (partial[0][tl][l] + partial[1][tl][l]) +
                (partial[2][tl][l] + partial[3][tl][l]) + bias;

    float mx = lgv;
#pragma unroll
    for (int off = 32; off; off >>= 1) mx = fmaxf(mx, __shfl_xor(mx, off));
    float ev = expf(lgv - mx);
    float sm = ev;
#pragma unroll
    for (int off = 32; off; off >>= 1) sm += __shfl_xor(sm, off);
    float p = ev / sm;

    // bitonic sort: descending by p, ties by ascending index
    float sp = p;
    int   si = l;
#pragma unroll
    for (int k = 2; k <= 64; k <<= 1) {
#pragma unroll
      for (int j = k >> 1; j > 0; j >>= 1) {
        float op = __shfl_xor(sp, j);
        int   oi = __shfl_xor(si, j);
        bool cmp  = (sp > op) || (sp == op && si < oi);
        bool keep = (cmp == (((l & k) == 0) == ((l & j) == 0)));
        if (!keep) { sp = op; si = oi; }
      }
    }

    // inclusive prefix sum
    float c = sp;
#pragma unroll
    for (int off = 1; off < 64; off <<= 1) {
      float tp = __shfl_up(c, off);
      if (l >= off) c += tp;
    }

    unsigned long long m = __ballot(c >= 0.8f);
    int kv = (m == 0ULL) ? NEXP : __ffsll(m);

    // ambiguity flags (margins >> split-bf16 logit error ~2e-5)
    float spn = __shfl_down(sp, 1);
    bool pairRisk = (l < kv) && (l < 63) && ((sp - spn) < 1e-3f * (sp + spn));
    bool cumRisk  = fabsf(c - 0.8f) < 3e-4f;
    bool flagged  = (__ballot(pairRisk || cumRisk) != 0ULL);

    bool sel = l < kv;
    const int tok = m0 + tl;
    size_t base = (size_t)tok * NEXP;
    out_exp[base + l]  = sel ? (float)si : -1.0f;
    out_prob[base + l] = sel ? sp : 0.0f;
    if (l == 0) {
      out_k[tok] = (float)kv;
      if (flagged) {
        unsigned int idx = atomicAdd(flag_count, 1u);
        flag_list[idx] = tok;
      }
    }
  }
}

// ---- Kernel 2: fp64 exact repair of flagged tokens -------------------------
__global__ __launch_bounds__(256) void router_repair(
    const float* __restrict__ x, const float* __restrict__ W,
    const float* __restrict__ b, const unsigned int* __restrict__ flag_count,
    const int* __restrict__ flag_list, float* __restrict__ out_exp,
    float* __restrict__ out_prob, float* __restrict__ out_k) {
  __shared__ double part[4][NEXP];
  const int t = threadIdx.x;
  const int e = t & 63;
  const int c = t >> 6;
  const int n = (int)*flag_count;

  for (int i = blockIdx.x; i < n; i += gridDim.x) {
    const int tok = flag_list[i];
    const float* xrow = x + (size_t)tok * HID;
    double s = 0.0;
    const int k0 = c * (HID / 4);
#pragma unroll 8
    for (int k = k0; k < k0 + HID / 4; ++k)
      s = fma((double)xrow[k], (double)W[(size_t)k * NEXP + e], s);
    part[c][e] = s;
    __syncthreads();

    if (t < 64) {
      double lgv = ((part[0][e] + part[1][e]) + part[2][e]) + part[3][e] +
                   (double)b[e];
      double mx = lgv;
#pragma unroll
      for (int off = 32; off; off >>= 1) mx = fmax(mx, __shfl_xor(mx, off));
      double ev = exp(lgv - mx);
      double sm = ev;
#pragma unroll
      for (int off = 32; off; off >>= 1) sm += __shfl_xor(sm, off);
      double p = ev / sm;

      double sp = p;
      int    si = e;
#pragma unroll
      for (int k = 2; k <= 64; k <<= 1) {
#pragma unroll
        for (int j = k >> 1; j > 0; j >>= 1) {
          double op = __shfl_xor(sp, j);
          int    oi = __shfl_xor(si, j);
          bool cmp  = (sp > op) || (sp == op && si < oi);
          bool keep = (cmp == (((e & k) == 0) == ((e & j) == 0)));
          if (!keep) { sp = op; si = oi; }
        }
      }

      double cc = sp;
#pragma unroll
      for (int off = 1; off < 64; off <<= 1) {
        double tp = __shfl_up(cc, off);
        if (e >= off) cc += tp;
      }

      unsigned long long m = __ballot(cc >= 0.8);
      int kv = (m == 0ULL) ? NEXP : __ffsll(m);

      bool sel = e < kv;
      size_t base = (size_t)tok * NEXP;
      out_exp[base + e]  = sel ? (float)si : -1.0f;
      out_prob[base + e] = sel ? (float)sp : 0.0f;
      if (e == 0) out_k[tok] = (float)kv;
    }
    __syncthreads();
  }
}

extern "C" void kernel_launch(void* const* d_in, const int* in_sizes, int n_in,
                              void* d_out, int out_size, void* d_ws,
                              size_t ws_size, hipStream_t stream) {
  const float* x = (const float*)d_in[0];
  const float* W = (const float*)d_in[1];
  const float* b = (const float*)d_in[2];

  float* out_exp  = (float*)d_out;
  float* out_prob = out_exp + (size_t)NTOK * NEXP;
  float* out_k    = out_prob + (size_t)NTOK * NEXP;

  short* wfh = (short*)d_ws;                                   // 512 KB
  short* wfl = (short*)((char*)d_ws + (size_t)512 * 1024);     // 512 KB
  unsigned int* flag_count = (unsigned int*)((char*)d_ws + (size_t)1024 * 1024);
  int* flag_list = (int*)((char*)d_ws + (size_t)1024 * 1024 + 256);

  hipMemsetAsync(flag_count, 0, 4, stream);

  wfrag_kernel<<<128, 256, 0, stream>>>(W, wfh, wfl);
  router_main<<<NTOK / 16, 256, 0, stream>>>(x, wfh, wfl, b, out_exp,
                                             out_prob, out_k, flag_count,
                                             flag_list);
  router_repair<<<128, 256, 0, stream>>>(x, W, b, flag_count, flag_list,
                                         out_exp, out_prob, out_k);
}